// Round 15
// baseline (118.591 us; speedup 1.0000x reference)
//
#include <hip/hip_runtime.h>

#define TS 20
#define BATCH 8192
#define LOG2E 1.4426950408889634f

typedef _Float16 half8 __attribute__((ext_vector_type(8)));
typedef float f32x4 __attribute__((ext_vector_type(4)));

__device__ __forceinline__ float fexp2(float x) {
#if __has_builtin(__builtin_amdgcn_exp2f)
    return __builtin_amdgcn_exp2f(x);
#else
    return exp2f(x);
#endif
}
// weights pre-scaled by log2e (sig) / 2log2e (tanh):
__device__ __forceinline__ float sig2(float zp)  { return __builtin_amdgcn_rcpf(1.0f + fexp2(-zp)); }
// tanh from a 2*log2e-scaled argument: tanh(c) where zp = 2*log2e*c
__device__ __forceinline__ float tanh2(float zp) { return 1.0f - 2.0f * __builtin_amdgcn_rcpf(1.0f + fexp2(zp)); }
// row swizzle for 16B LDS units
__device__ __forceinline__ int swz(int r) { return (r & 7) ^ (((r >> 3) & 1) << 2); }

// ============ Fused LSTM1+LSTM2+LN+FC, rotated + dedup'd loads ============
// R13 base (best: 76.9us). This round (resubmit of R14 — infra died before
// measurement): (1) B(t) reuses A(t+1)'s Hb[t&1] frag loads (identical
// addresses) -> -4 ds_read_b128/wave/window; (2) setprio(1) around the fused
// MFMA cluster; (3) c-state stored pre-scaled by 2*log2e
// (G = fma(-4L, r, 2L)) -> -1 v_mul per cell-step.
extern "C" __global__ __launch_bounds__(512, 1)
void fused_lstm_rot2_kernel(const float* __restrict__ x,
                            const float* __restrict__ Wih1, const float* __restrict__ Whh1,
                            const float* __restrict__ bih1, const float* __restrict__ bhh1,
                            const float* __restrict__ Wih2, const float* __restrict__ Whh2,
                            const float* __restrict__ bih2, const float* __restrict__ bhh2,
                            const float* __restrict__ gamma, const float* __restrict__ beta,
                            const float* __restrict__ W1fc, const float* __restrict__ b1fc,
                            const float* __restrict__ W2fc, const float* __restrict__ b2fc,
                            float* __restrict__ out)
{
    __shared__ __align__(16) _Float16 bf2l[4 * 4 * 6 * 64 * 8];  // L2 weight frags : 96 KB
    __shared__ __align__(16) _Float16 Hb[2][2][16][128];         // h1 dbuf, swizzled : 16 KB
    __shared__ __align__(16) _Float16 Hc[2][2][16][72];          // h2 dbuf : 9 KB
    __shared__ __align__(16) _Float16 Xb[32][328];               // x fp16 : 20.5 KB
    __shared__ float h2f[32][68];                                // final h2 : 8.5 KB

    const int tid  = threadIdx.x;
    const int lane = tid & 63;
    const int w    = tid >> 6;     // 0..7
    const int lrow = lane & 15;
    const int lgrp = lane >> 4;    // 0..3
    const int b0   = blockIdx.x * 32;

    // ---- L1 weights in VGPRs (80), pre-scaled ----
    half8 bf[4][5];
    float bias1[4];
#pragma unroll
    for (int g = 0; g < 4; ++g) {
        const float sc = (g == 2) ? 2.0f * LOG2E : LOG2E;
        const int n = g * 128 + w * 16 + lrow;
        bias1[g] = (bih1[n] + bhh1[n]) * sc;
#pragma unroll
        for (int ch = 0; ch < 5; ++ch) {
            half8 v;
            if (ch < 4) {
                const float4 p0 = *(const float4*)&Whh1[n * 128 + ch * 32 + lgrp * 8];
                const float4 p1 = *(const float4*)&Whh1[n * 128 + ch * 32 + lgrp * 8 + 4];
                v[0]=(_Float16)(p0.x*sc); v[1]=(_Float16)(p0.y*sc); v[2]=(_Float16)(p0.z*sc); v[3]=(_Float16)(p0.w*sc);
                v[4]=(_Float16)(p1.x*sc); v[5]=(_Float16)(p1.y*sc); v[6]=(_Float16)(p1.z*sc); v[7]=(_Float16)(p1.w*sc);
            } else if (lgrp < 2) {
                const float4 p0 = *(const float4*)&Wih1[n * 16 + lgrp * 8];
                const float4 p1 = *(const float4*)&Wih1[n * 16 + lgrp * 8 + 4];
                v[0]=(_Float16)(p0.x*sc); v[1]=(_Float16)(p0.y*sc); v[2]=(_Float16)(p0.z*sc); v[3]=(_Float16)(p0.w*sc);
                v[4]=(_Float16)(p1.x*sc); v[5]=(_Float16)(p1.y*sc); v[6]=(_Float16)(p1.z*sc); v[7]=(_Float16)(p1.w*sc);
            } else {
#pragma unroll
                for (int j = 0; j < 8; ++j) v[j] = (_Float16)0.0f;
            }
            bf[g][ch] = v;
        }
    }

    // ---- L2 bias + stage bf2l (waves 0..3 stage cellgroup w) ----
    const int cg = w & 3;
    const int mt = w >> 2;
    float bias2[4];
#pragma unroll
    for (int g = 0; g < 4; ++g) {
        const float sc = (g == 2) ? 2.0f * LOG2E : LOG2E;
        const int n = g * 64 + cg * 16 + lrow;
        bias2[g] = (bih2[n] + bhh2[n]) * sc;
    }
    if (w < 4) {
#pragma unroll
        for (int g = 0; g < 4; ++g) {
            const float sc = (g == 2) ? 2.0f * LOG2E : LOG2E;
            const int n = g * 64 + w * 16 + lrow;
#pragma unroll
            for (int ch = 0; ch < 6; ++ch) {
                const float4 p0 = (ch < 4) ? *(const float4*)&Wih2[n * 128 + ch * 32 + lgrp * 8]
                                           : *(const float4*)&Whh2[n * 64 + (ch - 4) * 32 + lgrp * 8];
                const float4 p1 = (ch < 4) ? *(const float4*)&Wih2[n * 128 + ch * 32 + lgrp * 8 + 4]
                                           : *(const float4*)&Whh2[n * 64 + (ch - 4) * 32 + lgrp * 8 + 4];
                half8 v;
                v[0]=(_Float16)(p0.x*sc); v[1]=(_Float16)(p0.y*sc); v[2]=(_Float16)(p0.z*sc); v[3]=(_Float16)(p0.w*sc);
                v[4]=(_Float16)(p1.x*sc); v[5]=(_Float16)(p1.y*sc); v[6]=(_Float16)(p1.z*sc); v[7]=(_Float16)(p1.w*sc);
                ((half8*)bf2l)[((w * 4 + g) * 6 + ch) * 64 + lane] = v;
            }
        }
    }

    // ---- zero h-state, stage x as fp16 ----
    for (int i = tid; i < 2 * 2 * 16 * 128; i += 512) (&Hb[0][0][0][0])[i] = (_Float16)0.0f;
    for (int i = tid; i < 2 * 2 * 16 * 72;  i += 512) (&Hc[0][0][0][0])[i] = (_Float16)0.0f;
    for (int i = tid; i < 32 * 320; i += 512) {
        const int r = i / 320, k = i % 320;
        Xb[r][k] = (_Float16)x[(size_t)(b0 + r) * 320 + k];
    }
    half8 kzero;
#pragma unroll
    for (int j = 0; j < 8; ++j) kzero[j] = (_Float16)0.0f;

    float c1[2][4] = {{0.f,0.f,0.f,0.f},{0.f,0.f,0.f,0.f}};   // pre-scaled: C = 2L*c
    float c2[4] = {0.f, 0.f, 0.f, 0.f};
    const int hu  = (w << 1) | (lrow >> 3);
    const int hlo = lrow & 7;
    const int szr = swz(lrow);
    const int cell2 = (cg << 4) | lrow;

    __syncthreads();          // staging visible

    // ---- A(0): h1(0) -> Hb[0] ----
    {
#pragma unroll
        for (int tile = 0; tile < 2; ++tile) {
            half8 a4 = (lgrp < 2) ? *(const half8*)&Xb[tile * 16 + lrow][lgrp * 8] : kzero;
            f32x4 z[4];
#pragma unroll
            for (int g = 0; g < 4; ++g) z[g] = (f32x4){bias1[g], bias1[g], bias1[g], bias1[g]};
            // h(-1)=0: only the x chunk contributes
#pragma unroll
            for (int g = 0; g < 4; ++g)
                z[g] = __builtin_amdgcn_mfma_f32_16x16x32_f16(a4, bf[g][4], z[g], 0, 0, 0);
#pragma unroll
            for (int j = 0; j < 4; ++j) {
                const float iv = sig2(z[0][j]);
                const float fv = sig2(z[1][j]);
                const float rg = __builtin_amdgcn_rcpf(1.0f + fexp2(z[2][j]));
                const float G  = fmaf(-4.0f * LOG2E, rg, 2.0f * LOG2E);     // 2L*tanh(zg)
                const float ov = sig2(z[3][j]);
                const float C  = fv * c1[tile][j] + iv * G;                  // C = 2L*c
                c1[tile][j] = C;
                const float h = ov * tanh2(C);
                const int m = (lgrp << 2) | j;
                Hb[0][tile][m][((hu ^ swz(m)) << 3) | hlo] = (_Float16)h;
            }
        }
    }
    __syncthreads();          // publish h1(0)

#pragma unroll 2
    for (int t = 0; t < TS - 1; ++t) {
        const int sB = t & 1;
        // ---- shared loads: A(t+1) frags (B reuses a[mt][0..3]) + Hc frags ----
        half8 a[2][5];
#pragma unroll
        for (int tile = 0; tile < 2; ++tile) {
#pragma unroll
            for (int ch = 0; ch < 4; ++ch)
                a[tile][ch] = *(const half8*)&Hb[sB][tile][lrow][(((ch << 2) | lgrp) ^ szr) * 8];
            a[tile][4] = (lgrp < 2) ? *(const half8*)&Xb[tile * 16 + lrow][(t + 1) * 16 + lgrp * 8] : kzero;
        }
        half8 hcf[2];
#pragma unroll
        for (int c2i = 0; c2i < 2; ++c2i)
            hcf[c2i] = *(const half8*)&Hc[sB ^ 1][mt][lrow][c2i * 32 + lgrp * 8];

        __builtin_amdgcn_s_setprio(1);
        // ---- B(t) MFMA: uses shared a[mt][0..3] + hcf ----
        f32x4 z2[4];
#pragma unroll
        for (int g = 0; g < 4; ++g) z2[g] = (f32x4){bias2[g], bias2[g], bias2[g], bias2[g]};
#pragma unroll
        for (int ch = 0; ch < 6; ++ch) {
            const half8 a2 = (ch < 4) ? a[mt][ch] : hcf[ch - 4];
#pragma unroll
            for (int g = 0; g < 4; ++g) {
                const half8 wf = ((const half8*)bf2l)[((cg * 4 + g) * 6 + ch) * 64 + lane];
                z2[g] = __builtin_amdgcn_mfma_f32_16x16x32_f16(a2, wf, z2[g], 0, 0, 0);
            }
        }
        // ---- A(t+1) MFMA ----
        f32x4 z[2][4];
#pragma unroll
        for (int tile = 0; tile < 2; ++tile)
#pragma unroll
            for (int g = 0; g < 4; ++g) z[tile][g] = (f32x4){bias1[g], bias1[g], bias1[g], bias1[g]};
#pragma unroll
        for (int ch = 0; ch < 5; ++ch)
#pragma unroll
            for (int tile = 0; tile < 2; ++tile)
#pragma unroll
                for (int g = 0; g < 4; ++g)
                    z[tile][g] = __builtin_amdgcn_mfma_f32_16x16x32_f16(a[tile][ch], bf[g][ch], z[tile][g], 0, 0, 0);
        __builtin_amdgcn_s_setprio(0);

        // ---- B(t) activations + Hc store ----
#pragma unroll
        for (int j = 0; j < 4; ++j) {
            const float iv = sig2(z2[0][j]);
            const float fv = sig2(z2[1][j]);
            const float rg = __builtin_amdgcn_rcpf(1.0f + fexp2(z2[2][j]));
            const float G  = fmaf(-4.0f * LOG2E, rg, 2.0f * LOG2E);
            const float ov = sig2(z2[3][j]);
            const float C  = fv * c2[j] + iv * G;
            c2[j] = C;
            const float h = ov * tanh2(C);
            const int m = (lgrp << 2) | j;
            Hc[sB][mt][m][cell2] = (_Float16)h;
        }
        // ---- A(t+1) activations + Hb store ----
#pragma unroll
        for (int tile = 0; tile < 2; ++tile)
#pragma unroll
            for (int j = 0; j < 4; ++j) {
                const float iv = sig2(z[tile][0][j]);
                const float fv = sig2(z[tile][1][j]);
                const float rg = __builtin_amdgcn_rcpf(1.0f + fexp2(z[tile][2][j]));
                const float G  = fmaf(-4.0f * LOG2E, rg, 2.0f * LOG2E);
                const float ov = sig2(z[tile][3][j]);
                const float C  = fv * c1[tile][j] + iv * G;
                c1[tile][j] = C;
                const float h = ov * tanh2(C);
                const int m = (lgrp << 2) | j;
                Hb[sB ^ 1][tile][m][((hu ^ swz(m)) << 3) | hlo] = (_Float16)h;
            }
        __syncthreads();
    }

    // ---- final B(TS-1) -> h2f ----
    {
        const int sB = (TS - 1) & 1;
        f32x4 z2[4];
#pragma unroll
        for (int g = 0; g < 4; ++g) z2[g] = (f32x4){bias2[g], bias2[g], bias2[g], bias2[g]};
#pragma unroll
        for (int ch = 0; ch < 6; ++ch) {
            const half8 a2 = (ch < 4)
                ? *(const half8*)&Hb[sB][mt][lrow][(((ch << 2) | lgrp) ^ szr) * 8]
                : *(const half8*)&Hc[sB ^ 1][mt][lrow][(ch - 4) * 32 + lgrp * 8];
#pragma unroll
            for (int g = 0; g < 4; ++g) {
                const half8 wf = ((const half8*)bf2l)[((cg * 4 + g) * 6 + ch) * 64 + lane];
                z2[g] = __builtin_amdgcn_mfma_f32_16x16x32_f16(a2, wf, z2[g], 0, 0, 0);
            }
        }
#pragma unroll
        for (int j = 0; j < 4; ++j) {
            const float iv = sig2(z2[0][j]);
            const float fv = sig2(z2[1][j]);
            const float rg = __builtin_amdgcn_rcpf(1.0f + fexp2(z2[2][j]));
            const float G  = fmaf(-4.0f * LOG2E, rg, 2.0f * LOG2E);
            const float ov = sig2(z2[3][j]);
            const float C  = fv * c2[j] + iv * G;
            c2[j] = C;
            const float h = ov * tanh2(C);
            const int m = (lgrp << 2) | j;
            h2f[(mt << 4) | m][cell2] = h;
        }
    }
    __syncthreads();

    // ---- epilogue: LayerNorm + FC1(relu) + FC2 ----
    {
        const int m = tid >> 4, q = tid & 15;
        const float v0 = h2f[m][q * 4 + 0];
        const float v1 = h2f[m][q * 4 + 1];
        const float v2 = h2f[m][q * 4 + 2];
        const float v3 = h2f[m][q * 4 + 3];
        float ssum = v0 + v1 + v2 + v3;
        ssum += __shfl_xor(ssum, 1); ssum += __shfl_xor(ssum, 2);
        ssum += __shfl_xor(ssum, 4); ssum += __shfl_xor(ssum, 8);
        const float mean = ssum * (1.0f / 64.0f);
        const float d0 = v0 - mean, d1 = v1 - mean, d2 = v2 - mean, d3 = v3 - mean;
        float vs = d0 * d0 + d1 * d1 + d2 * d2 + d3 * d3;
        vs += __shfl_xor(vs, 1); vs += __shfl_xor(vs, 2);
        vs += __shfl_xor(vs, 4); vs += __shfl_xor(vs, 8);
        const float rstd = rsqrtf(vs * (1.0f / 64.0f) + 1e-5f);
        const int i0 = q * 4;
        h2f[m][i0 + 0] = d0 * rstd * gamma[i0 + 0] + beta[i0 + 0];
        h2f[m][i0 + 1] = d1 * rstd * gamma[i0 + 1] + beta[i0 + 1];
        h2f[m][i0 + 2] = d2 * rstd * gamma[i0 + 2] + beta[i0 + 2];
        h2f[m][i0 + 3] = d3 * rstd * gamma[i0 + 3] + beta[i0 + 3];
    }
    __syncthreads();
    {
        const int o = tid & 31;
        const int mgrp = tid >> 5;    // 0..15
#pragma unroll
        for (int rr = 0; rr < 2; ++rr) {
            const int m = mgrp + rr * 16;
            float acc = b1fc[o];
#pragma unroll 8
            for (int k = 0; k < 64; ++k) acc += h2f[m][k] * W1fc[o * 64 + k];
            const float hv = fmaxf(acc, 0.0f);
            float p = hv * W2fc[o];
            p += __shfl_xor(p, 1); p += __shfl_xor(p, 2);
            p += __shfl_xor(p, 4); p += __shfl_xor(p, 8); p += __shfl_xor(p, 16);
            if (o == 0) out[b0 + m] = p + b2fc[0];
        }
    }
}

extern "C" void kernel_launch(void* const* d_in, const int* in_sizes, int n_in,
                              void* d_out, int out_size, void* d_ws, size_t ws_size,
                              hipStream_t stream) {
    (void)in_sizes; (void)n_in; (void)d_ws; (void)ws_size; (void)out_size;
    const float* x_p    = (const float*)d_in[0];
    const float* Wih1_p = (const float*)d_in[1];
    const float* Whh1_p = (const float*)d_in[2];
    const float* bih1_p = (const float*)d_in[3];
    const float* bhh1_p = (const float*)d_in[4];
    const float* Wih2_p = (const float*)d_in[5];
    const float* Whh2_p = (const float*)d_in[6];
    const float* bih2_p = (const float*)d_in[7];
    const float* bhh2_p = (const float*)d_in[8];
    const float* gamma_p = (const float*)d_in[9];
    const float* beta_p  = (const float*)d_in[10];
    const float* W1_p   = (const float*)d_in[11];
    const float* b1_p   = (const float*)d_in[12];
    const float* W2_p   = (const float*)d_in[13];
    const float* b2_p   = (const float*)d_in[14];
    float* out_p = (float*)d_out;

    fused_lstm_rot2_kernel<<<dim3(BATCH / 32), dim3(512), 0, stream>>>(
        x_p, Wih1_p, Whh1_p, bih1_p, bhh1_p,
        Wih2_p, Whh2_p, bih2_p, bhh2_p,
        gamma_p, beta_p, W1_p, b1_p, W2_p, b2_p, out_p);
}

// Round 16
// 76.965 us; speedup vs baseline: 1.5408x; 1.5408x over previous
//
#include <hip/hip_runtime.h>

#define TS 20
#define BATCH 8192
#define LOG2E 1.4426950408889634f

typedef _Float16 half8 __attribute__((ext_vector_type(8)));
typedef float f32x4 __attribute__((ext_vector_type(4)));

__device__ __forceinline__ float fexp2(float x) {
#if __has_builtin(__builtin_amdgcn_exp2f)
    return __builtin_amdgcn_exp2f(x);
#else
    return exp2f(x);
#endif
}
// weights pre-scaled by log2e (sig) / 2log2e (tanh):
__device__ __forceinline__ float sig2(float zp)  { return __builtin_amdgcn_rcpf(1.0f + fexp2(-zp)); }
// tanh from a 2*log2e-scaled argument
__device__ __forceinline__ float tanh2(float zp) { return 1.0f - 2.0f * __builtin_amdgcn_rcpf(1.0f + fexp2(zp)); }
// row swizzle for 16B LDS units
__device__ __forceinline__ int swz(int r) { return (r & 7) ^ (((r >> 3) & 1) << 2); }

// ============ Fused LSTM1+LSTM2+LN+FC (R13 structure restored) ============
// R13 = best measured (76.9us, VGPR 104, no spill). R15's fused-lifetime
// dedup spilled (demand ~196 > cap 128, WRITE 289MB). This round: R13 verbatim
// + only zero-register tweaks: (a) c-state pre-scaled by 2*log2e (-1 v_mul
// per cell-update), (b) setprio(1) around each phase's MFMA run separately.
extern "C" __global__ __launch_bounds__(512, 1)
void fused_lstm_rot3_kernel(const float* __restrict__ x,
                            const float* __restrict__ Wih1, const float* __restrict__ Whh1,
                            const float* __restrict__ bih1, const float* __restrict__ bhh1,
                            const float* __restrict__ Wih2, const float* __restrict__ Whh2,
                            const float* __restrict__ bih2, const float* __restrict__ bhh2,
                            const float* __restrict__ gamma, const float* __restrict__ beta,
                            const float* __restrict__ W1fc, const float* __restrict__ b1fc,
                            const float* __restrict__ W2fc, const float* __restrict__ b2fc,
                            float* __restrict__ out)
{
    __shared__ __align__(16) _Float16 bf2l[4 * 4 * 6 * 64 * 8];  // L2 weight frags : 96 KB
    __shared__ __align__(16) _Float16 Hb[2][2][16][128];         // h1 dbuf, swizzled : 16 KB
    __shared__ __align__(16) _Float16 Hc[2][2][16][72];          // h2 dbuf : 9 KB
    __shared__ __align__(16) _Float16 Xb[32][328];               // x fp16 : 20.5 KB
    __shared__ float h2f[32][68];                                // final h2 : 8.5 KB

    const int tid  = threadIdx.x;
    const int lane = tid & 63;
    const int w    = tid >> 6;     // 0..7
    const int lrow = lane & 15;
    const int lgrp = lane >> 4;    // 0..3
    const int b0   = blockIdx.x * 32;

    // ---- L1 weights in VGPRs (80), pre-scaled ----
    half8 bf[4][5];
    float bias1[4];
#pragma unroll
    for (int g = 0; g < 4; ++g) {
        const float sc = (g == 2) ? 2.0f * LOG2E : LOG2E;
        const int n = g * 128 + w * 16 + lrow;
        bias1[g] = (bih1[n] + bhh1[n]) * sc;
#pragma unroll
        for (int ch = 0; ch < 5; ++ch) {
            half8 v;
            if (ch < 4) {
                const float4 p0 = *(const float4*)&Whh1[n * 128 + ch * 32 + lgrp * 8];
                const float4 p1 = *(const float4*)&Whh1[n * 128 + ch * 32 + lgrp * 8 + 4];
                v[0]=(_Float16)(p0.x*sc); v[1]=(_Float16)(p0.y*sc); v[2]=(_Float16)(p0.z*sc); v[3]=(_Float16)(p0.w*sc);
                v[4]=(_Float16)(p1.x*sc); v[5]=(_Float16)(p1.y*sc); v[6]=(_Float16)(p1.z*sc); v[7]=(_Float16)(p1.w*sc);
            } else if (lgrp < 2) {
                const float4 p0 = *(const float4*)&Wih1[n * 16 + lgrp * 8];
                const float4 p1 = *(const float4*)&Wih1[n * 16 + lgrp * 8 + 4];
                v[0]=(_Float16)(p0.x*sc); v[1]=(_Float16)(p0.y*sc); v[2]=(_Float16)(p0.z*sc); v[3]=(_Float16)(p0.w*sc);
                v[4]=(_Float16)(p1.x*sc); v[5]=(_Float16)(p1.y*sc); v[6]=(_Float16)(p1.z*sc); v[7]=(_Float16)(p1.w*sc);
            } else {
#pragma unroll
                for (int j = 0; j < 8; ++j) v[j] = (_Float16)0.0f;
            }
            bf[g][ch] = v;
        }
    }

    // ---- L2 bias + stage bf2l (waves 0..3 stage cellgroup w) ----
    const int cg = w & 3;
    const int mt = w >> 2;
    float bias2[4];
#pragma unroll
    for (int g = 0; g < 4; ++g) {
        const float sc = (g == 2) ? 2.0f * LOG2E : LOG2E;
        const int n = g * 64 + cg * 16 + lrow;
        bias2[g] = (bih2[n] + bhh2[n]) * sc;
    }
    if (w < 4) {
#pragma unroll
        for (int g = 0; g < 4; ++g) {
            const float sc = (g == 2) ? 2.0f * LOG2E : LOG2E;
            const int n = g * 64 + w * 16 + lrow;
#pragma unroll
            for (int ch = 0; ch < 6; ++ch) {
                const float4 p0 = (ch < 4) ? *(const float4*)&Wih2[n * 128 + ch * 32 + lgrp * 8]
                                           : *(const float4*)&Whh2[n * 64 + (ch - 4) * 32 + lgrp * 8];
                const float4 p1 = (ch < 4) ? *(const float4*)&Wih2[n * 128 + ch * 32 + lgrp * 8 + 4]
                                           : *(const float4*)&Whh2[n * 64 + (ch - 4) * 32 + lgrp * 8 + 4];
                half8 v;
                v[0]=(_Float16)(p0.x*sc); v[1]=(_Float16)(p0.y*sc); v[2]=(_Float16)(p0.z*sc); v[3]=(_Float16)(p0.w*sc);
                v[4]=(_Float16)(p1.x*sc); v[5]=(_Float16)(p1.y*sc); v[6]=(_Float16)(p1.z*sc); v[7]=(_Float16)(p1.w*sc);
                ((half8*)bf2l)[((w * 4 + g) * 6 + ch) * 64 + lane] = v;
            }
        }
    }

    // ---- zero h-state, stage x as fp16 ----
    for (int i = tid; i < 2 * 2 * 16 * 128; i += 512) (&Hb[0][0][0][0])[i] = (_Float16)0.0f;
    for (int i = tid; i < 2 * 2 * 16 * 72;  i += 512) (&Hc[0][0][0][0])[i] = (_Float16)0.0f;
    for (int i = tid; i < 32 * 320; i += 512) {
        const int r = i / 320, k = i % 320;
        Xb[r][k] = (_Float16)x[(size_t)(b0 + r) * 320 + k];
    }
    half8 kzero;
#pragma unroll
    for (int j = 0; j < 8; ++j) kzero[j] = (_Float16)0.0f;

    float c1[2][4] = {{0.f,0.f,0.f,0.f},{0.f,0.f,0.f,0.f}};   // pre-scaled: C = 2L*c
    float c2[4] = {0.f, 0.f, 0.f, 0.f};
    const int hu  = (w << 1) | (lrow >> 3);
    const int hlo = lrow & 7;
    const int szr = swz(lrow);
    const int cell2 = (cg << 4) | lrow;

    // phase A(tt): h1(tt) from Hb[(tt&1)^1] + Xb[:,tt*16..] -> Hb[tt&1]
    auto phaseA = [&](int tt) {
        const int sA = tt & 1;
#pragma unroll
        for (int tile = 0; tile < 2; ++tile) {
            half8 a[5];
#pragma unroll
            for (int ch = 0; ch < 4; ++ch)
                a[ch] = *(const half8*)&Hb[sA ^ 1][tile][lrow][(((ch << 2) | lgrp) ^ szr) * 8];
            a[4] = (lgrp < 2) ? *(const half8*)&Xb[tile * 16 + lrow][tt * 16 + lgrp * 8] : kzero;
            f32x4 z[4];
#pragma unroll
            for (int g = 0; g < 4; ++g) z[g] = (f32x4){bias1[g], bias1[g], bias1[g], bias1[g]};
            __builtin_amdgcn_s_setprio(1);
#pragma unroll
            for (int ch = 0; ch < 5; ++ch)
#pragma unroll
                for (int g = 0; g < 4; ++g)
                    z[g] = __builtin_amdgcn_mfma_f32_16x16x32_f16(a[ch], bf[g][ch], z[g], 0, 0, 0);
            __builtin_amdgcn_s_setprio(0);
#pragma unroll
            for (int j = 0; j < 4; ++j) {
                const float iv = sig2(z[0][j]);
                const float fv = sig2(z[1][j]);
                const float rg = __builtin_amdgcn_rcpf(1.0f + fexp2(z[2][j]));
                const float G  = fmaf(-4.0f * LOG2E, rg, 2.0f * LOG2E);     // 2L*tanh(zg)
                const float ov = sig2(z[3][j]);
                const float C  = fv * c1[tile][j] + iv * G;                  // C = 2L*c
                c1[tile][j] = C;
                const float h = ov * tanh2(C);
                const int m = (lgrp << 2) | j;
                Hb[sA][tile][m][((hu ^ swz(m)) << 3) | hlo] = (_Float16)h;
            }
        }
    };
    // phase B(tt): h2(tt) from Hb[tt&1] + Hc[(tt&1)^1] -> Hc[tt&1] (+h2f if last)
    auto phaseB = [&](int tt, bool last) {
        const int sB = tt & 1;
        f32x4 z2[4];
#pragma unroll
        for (int g = 0; g < 4; ++g) z2[g] = (f32x4){bias2[g], bias2[g], bias2[g], bias2[g]};
        __builtin_amdgcn_s_setprio(1);
#pragma unroll
        for (int ch = 0; ch < 6; ++ch) {
            const half8 a2 = (ch < 4)
                ? *(const half8*)&Hb[sB][mt][lrow][(((ch << 2) | lgrp) ^ szr) * 8]
                : *(const half8*)&Hc[sB ^ 1][mt][lrow][(ch - 4) * 32 + lgrp * 8];
#pragma unroll
            for (int g = 0; g < 4; ++g) {
                const half8 wf = ((const half8*)bf2l)[((cg * 4 + g) * 6 + ch) * 64 + lane];
                z2[g] = __builtin_amdgcn_mfma_f32_16x16x32_f16(a2, wf, z2[g], 0, 0, 0);
            }
        }
        __builtin_amdgcn_s_setprio(0);
#pragma unroll
        for (int j = 0; j < 4; ++j) {
            const float iv = sig2(z2[0][j]);
            const float fv = sig2(z2[1][j]);
            const float rg = __builtin_amdgcn_rcpf(1.0f + fexp2(z2[2][j]));
            const float G  = fmaf(-4.0f * LOG2E, rg, 2.0f * LOG2E);
            const float ov = sig2(z2[3][j]);
            const float C  = fv * c2[j] + iv * G;
            c2[j] = C;
            const float h = ov * tanh2(C);
            const int m = (lgrp << 2) | j;
            Hc[sB][mt][m][cell2] = (_Float16)h;
            if (last) h2f[(mt << 4) | m][cell2] = h;
        }
    };

    __syncthreads();          // staging visible
    phaseA(0);                // h1(0)
    __syncthreads();          // publish h1(0)

#pragma unroll 2
    for (int t = 0; t < TS - 1; ++t) {
        phaseB(t, false);
        phaseA(t + 1);
        __syncthreads();
    }
    phaseB(TS - 1, true);
    __syncthreads();

    // ---- epilogue: LayerNorm + FC1(relu) + FC2 ----
    {
        const int m = tid >> 4, q = tid & 15;
        const float v0 = h2f[m][q * 4 + 0];
        const float v1 = h2f[m][q * 4 + 1];
        const float v2 = h2f[m][q * 4 + 2];
        const float v3 = h2f[m][q * 4 + 3];
        float ssum = v0 + v1 + v2 + v3;
        ssum += __shfl_xor(ssum, 1); ssum += __shfl_xor(ssum, 2);
        ssum += __shfl_xor(ssum, 4); ssum += __shfl_xor(ssum, 8);
        const float mean = ssum * (1.0f / 64.0f);
        const float d0 = v0 - mean, d1 = v1 - mean, d2 = v2 - mean, d3 = v3 - mean;
        float vs = d0 * d0 + d1 * d1 + d2 * d2 + d3 * d3;
        vs += __shfl_xor(vs, 1); vs += __shfl_xor(vs, 2);
        vs += __shfl_xor(vs, 4); vs += __shfl_xor(vs, 8);
        const float rstd = rsqrtf(vs * (1.0f / 64.0f) + 1e-5f);
        const int i0 = q * 4;
        h2f[m][i0 + 0] = d0 * rstd * gamma[i0 + 0] + beta[i0 + 0];
        h2f[m][i0 + 1] = d1 * rstd * gamma[i0 + 1] + beta[i0 + 1];
        h2f[m][i0 + 2] = d2 * rstd * gamma[i0 + 2] + beta[i0 + 2];
        h2f[m][i0 + 3] = d3 * rstd * gamma[i0 + 3] + beta[i0 + 3];
    }
    __syncthreads();
    {
        const int o = tid & 31;
        const int mgrp = tid >> 5;    // 0..15
#pragma unroll
        for (int rr = 0; rr < 2; ++rr) {
            const int m = mgrp + rr * 16;
            float acc = b1fc[o];
#pragma unroll 8
            for (int k = 0; k < 64; ++k) acc += h2f[m][k] * W1fc[o * 64 + k];
            const float hv = fmaxf(acc, 0.0f);
            float p = hv * W2fc[o];
            p += __shfl_xor(p, 1); p += __shfl_xor(p, 2);
            p += __shfl_xor(p, 4); p += __shfl_xor(p, 8); p += __shfl_xor(p, 16);
            if (o == 0) out[b0 + m] = p + b2fc[0];
        }
    }
}

extern "C" void kernel_launch(void* const* d_in, const int* in_sizes, int n_in,
                              void* d_out, int out_size, void* d_ws, size_t ws_size,
                              hipStream_t stream) {
    (void)in_sizes; (void)n_in; (void)d_ws; (void)ws_size; (void)out_size;
    const float* x_p    = (const float*)d_in[0];
    const float* Wih1_p = (const float*)d_in[1];
    const float* Whh1_p = (const float*)d_in[2];
    const float* bih1_p = (const float*)d_in[3];
    const float* bhh1_p = (const float*)d_in[4];
    const float* Wih2_p = (const float*)d_in[5];
    const float* Whh2_p = (const float*)d_in[6];
    const float* bih2_p = (const float*)d_in[7];
    const float* bhh2_p = (const float*)d_in[8];
    const float* gamma_p = (const float*)d_in[9];
    const float* beta_p  = (const float*)d_in[10];
    const float* W1_p   = (const float*)d_in[11];
    const float* b1_p   = (const float*)d_in[12];
    const float* W2_p   = (const float*)d_in[13];
    const float* b2_p   = (const float*)d_in[14];
    float* out_p = (float*)d_out;

    fused_lstm_rot3_kernel<<<dim3(BATCH / 32), dim3(512), 0, stream>>>(
        x_p, Wih1_p, Whh1_p, bih1_p, bhh1_p,
        Wih2_p, Whh2_p, bih2_p, bhh2_p,
        gamma_p, beta_p, W1_p, b1_p, W2_p, b2_p, out_p);
}